// Round 4
// baseline (412.047 us; speedup 1.0000x reference)
//
#include <hip/hip_runtime.h>
#include <hip/hip_bf16.h>
#include <math.h>

#define B_ 8
#define Q_ 100
#define T_ 50
#define HW_ 65536

// ---------------- legacy (atomic) fallback path constants ----------------
#define NSEG 64
#define SEG (HW_ / NSEG)
#define NK32 (SEG / 32)
#define NSTR 52

#define DSZ (B_ * Q_ * NSTR)
#define WS_D1 0
#define WS_D2 DSZ
#define WS_SNEG (2 * DSZ)
#define WS_ST (2 * DSZ + B_ * Q_)
#define WS_TOTAL (2 * DSZ + B_ * Q_ + B_ * T_)

// ---------------- partial-store path constants (tiers A and B) ----------------
#define PSEG 128
#define SEGP (HW_ / PSEG)          // 512 K per block
#define NK32P (SEGP / 32)          // 16 K-steps of 32
#define PROWS 101
#define PCOLS 52
#define PTILE ((size_t)PROWS * PCOLS)          // 5252
#define PBLK ((size_t)B_ * PTILE)              // 42016 floats per seg per array
#define D2OFF ((size_t)PSEG * PBLK)
#define WS_NEEDED_BYTES (2ull * D2OFF * 4ull)  // 43,024,384 B (tier B)

// tier A adds a t-bitmask: 8 b x 64 rows x 2048 words (rows 50..63 synthetic:
// row 50 = all-ones for the ssum column, 51..63 zero padding -> no clamping)
#define BITS_WORDS (B_ * 64 * 2048)            // 1,048,576 words = 4 MB
#define BITS_FOFF (2 * D2OFF)                  // float offset of bitmask
#define WS2_NEEDED_BYTES ((2ull * D2OFF + (unsigned long long)BITS_WORDS) * 4ull)

typedef __attribute__((ext_vector_type(8))) short bf16x8;
typedef __attribute__((ext_vector_type(4))) float f32x4;

__device__ __forceinline__ unsigned short f2bf(float f) {
    union { float f; unsigned u; } v; v.f = f;
    unsigned r = v.u + 0x7FFF + ((v.u >> 16) & 1);
    return (unsigned short)(r >> 16);
}

// packed pair bf16(a) | bf16(b)<<16 — lowers to v_cvt_pk_bf16_f32 (1 op)
__device__ __forceinline__ unsigned pkbf(float a, float b) {
    float2 f2; f2.x = a; f2.y = b;
    __hip_bfloat162 h2 = __float22bfloat162_rn(f2);
    unsigned u; __builtin_memcpy(&u, &h2, 4); return u;
}

// ======================= tier A: bitmask pre-pass =======================
// One wave per 64 consecutive k of one (b,row): ballot -> 2 bitmask words.
// Rows >= T_ are synthetic (row 50 = ones, 51..63 = zero), no tgt reads.
#define PACK_GROUPS (B_ * 64 * (HW_ / 64))     // 524,288 wave-groups
__global__ __launch_bounds__(256) void pack_t(const int* __restrict__ tgt,
                                              unsigned* __restrict__ bits) {
    int wid = (blockIdx.x * blockDim.x + threadIdx.x) >> 6;
    int lane = threadIdx.x & 63;
    int nw = (gridDim.x * blockDim.x) >> 6;
    for (int g = wid; g < PACK_GROUPS; g += nw) {
        int b = g >> 16;                 // / (64*1024)
        int row = (g >> 10) & 63;
        int kbase = (g & 1023) << 6;
        int v;
        if (row < T_) v = tgt[((size_t)b * T_ + row) * HW_ + kbase + lane];
        else v = (row == T_) ? 1 : 0;
        unsigned long long mask = __ballot(v != 0);
        size_t widx = ((size_t)(b * 64 + row) << 11) + (kbase >> 5);
        if (lane == 0) bits[widx] = (unsigned)mask;
        if (lane == 32) bits[widx + 1] = (unsigned)(mask >> 32);
    }
}

// ======================= tier A main kernel =======================
// Register-diet rebuild of the fused GEMM. t comes from the 4 MB bitmask
// (8 VGPR of buffers instead of 64); x->bf16 via v_cvt_pk. AGPR accs = 64,
// so __launch_bounds__(256,3) caps vgpr+agpr <= ~168 -> 3 waves/SIMD
// (round 2/3 measured 2 waves/SIMD at 120+64 regs = the occupancy cap).
__global__ __launch_bounds__(256, 3) void gemm_fused_p2(const float* __restrict__ pred,
                                                        const unsigned* __restrict__ bits,
                                                        float* __restrict__ ws) {
    const int seg = blockIdx.x;
    const int b   = blockIdx.y;
    const int tid = threadIdx.x;
    const int wave = tid >> 6;
    const int lane = tid & 63;
    const int quad = lane >> 4;
    const int l16  = lane & 15;

    // A (x) pointers; only mt=1 can hit the ones-row (m==100)
    const float* xptr[2];
#pragma unroll
    for (int mt = 0; mt < 2; ++mt) {
        int m = (wave + mt * 4) * 16 + l16;
        int mr = m < Q_ ? m : Q_ - 1;
        xptr[mt] = pred + ((size_t)b * Q_ + mr) * HW_ + (size_t)seg * SEGP + quad * 8;
    }
    const int aones = ((wave + 4) * 16 + l16) == Q_;

    // t bitmask pointers: n = nt*16+l16 spans 0..63 exactly (rows padded)
    const unsigned* wp[4];
#pragma unroll
    for (int nt = 0; nt < 4; ++nt) {
        int n = nt * 16 + l16;
        wp[nt] = bits + ((size_t)(b * 64 + n) << 11) + (size_t)seg * NK32P;
    }

    f32x4 accx[2][4], accs[2][4];
#pragma unroll
    for (int mt = 0; mt < 2; ++mt)
#pragma unroll
        for (int nt = 0; nt < 4; ++nt) {
            accx[mt][nt] = (f32x4)(0.f);
            accs[mt][nt] = (f32x4)(0.f);
        }
    float sneg[2] = {0.f, 0.f};

    float4   xrb[2][2][2];
    unsigned wrb[2][4];

    auto loadraw = [&](int ch, float4 xr[2][2], unsigned wr[4]) {
#pragma unroll
        for (int nt = 0; nt < 4; ++nt) wr[nt] = wp[nt][ch];
        const int k = ch * 32;
#pragma unroll
        for (int mt = 0; mt < 2; ++mt) {
            xr[mt][0] = *(const float4*)(xptr[mt] + k);
            xr[mt][1] = *(const float4*)(xptr[mt] + k + 4);
        }
    };

    auto compute = [&](float4 xr[2][2], unsigned wr[4]) {
        bf16x8 tf[4];
#pragma unroll
        for (int nt = 0; nt < 4; ++nt) {
            unsigned mw = (wr[nt] >> (quad << 3)) & 0xFFu;
            unsigned uu[4];
#pragma unroll
            for (int j = 0; j < 4; ++j) {
                uu[j] = ((mw & 1u) * 0x3F80u) | (((mw & 2u) * 0x3F80u) << 15);
                mw >>= 2;
            }
            __builtin_memcpy(&tf[nt], uu, 16);
        }
#pragma unroll
        for (int mt = 0; mt < 2; ++mt) {
            float xv8[8], sg8[8];
            float sp = 0.f;
#pragma unroll
            for (int h = 0; h < 2; ++h)
#pragma unroll
                for (int e = 0; e < 4; ++e) {
                    int i = h * 4 + e;
                    float x = (&xr[mt][h].x)[e];
                    xv8[i] = x;
                    float ax = fabsf(x);
                    float ee = __expf(-ax);
                    float d = 1.f + ee;
                    float r1 = __builtin_amdgcn_rcpf(d);
                    sg8[i] = (x >= 0.f) ? r1 : ee * r1;                // sigmoid
                    sp += fmaxf(x, 0.f) + 0.69314718056f * __log2f(d); // softplus
                }
            sneg[mt] += sp;
            unsigned xu[4], su[4];
#pragma unroll
            for (int j = 0; j < 4; ++j) {
                xu[j] = pkbf(xv8[2 * j], xv8[2 * j + 1]);
                su[j] = pkbf(sg8[2 * j], sg8[2 * j + 1]);
            }
            if (mt == 1) {
#pragma unroll
                for (int j = 0; j < 4; ++j) {
                    xu[j] = aones ? 0x3F803F80u : xu[j];
                    su[j] = aones ? 0x3F803F80u : su[j];
                }
            }
            bf16x8 xf, sf;
            __builtin_memcpy(&xf, xu, 16);
            __builtin_memcpy(&sf, su, 16);
#pragma unroll
            for (int nt = 0; nt < 4; ++nt) {
                accx[mt][nt] = __builtin_amdgcn_mfma_f32_16x16x32_bf16(xf, tf[nt], accx[mt][nt], 0, 0, 0);
                accs[mt][nt] = __builtin_amdgcn_mfma_f32_16x16x32_bf16(sf, tf[nt], accs[mt][nt], 0, 0, 0);
            }
        }
    };

    loadraw(0, xrb[0], wrb[0]);
#pragma unroll 2
    for (int ch = 0; ch < NK32P; ++ch) {
        const int cb = ch & 1;
        if (ch + 1 < NK32P) loadraw(ch + 1, xrb[cb ^ 1], wrb[cb ^ 1]);
        compute(xrb[cb], wrb[cb]);
    }

    // ---- epilogue: coalesced partial stores, zero atomics ----
    float* d1 = ws + (size_t)(seg * B_ + b) * PTILE;
    float* d2 = d1 + D2OFF;

#pragma unroll
    for (int mt = 0; mt < 2; ++mt) {
        float v = sneg[mt];
        v += __shfl_xor(v, 16);
        v += __shfl_xor(v, 32);
        int m = (wave + mt * 4) * 16 + l16;
        if (quad == 0 && m < Q_) d1[(size_t)m * PCOLS + 51] = v;
    }
#pragma unroll
    for (int mt = 0; mt < 2; ++mt) {
        int mtile = (wave + mt * 4) * 16;
#pragma unroll
        for (int nt = 0; nt < 4; ++nt) {
            int n = nt * 16 + l16;
#pragma unroll
            for (int r = 0; r < 4; ++r) {
                int m = mtile + quad * 4 + r;
                if (m <= Q_ && n <= T_) {
                    size_t idx = (size_t)m * PCOLS + n;
                    d1[idx] = accx[mt][nt][r];
                    d2[idx] = accs[mt][nt][r];
                }
            }
        }
    }
}

// ======================= tier B main kernel (round-3, verbatim) =======================
__global__ __launch_bounds__(256, 2) void gemm_fused_p(const float* __restrict__ pred,
                                                       const int* __restrict__ tgt,
                                                       float* __restrict__ ws) {
    const int seg = blockIdx.x;
    const int b   = blockIdx.y;
    const int tid = threadIdx.x;
    const int wave = tid >> 6;
    const int lane = tid & 63;
    const int quad = lane >> 4;
    const int l16  = lane & 15;

    const float* xptr[2];
    int aones[2];
#pragma unroll
    for (int mt = 0; mt < 2; ++mt) {
        int m = (wave + mt * 4) * 16 + l16;
        aones[mt] = (m == Q_);
        int mr = m < Q_ ? m : Q_ - 1;
        xptr[mt] = pred + ((size_t)b * Q_ + mr) * HW_ + (size_t)seg * SEGP + quad * 8;
    }
    const int* tptr[4];
    short onesv[4];
#pragma unroll
    for (int nt = 0; nt < 4; ++nt) {
        int n = nt * 16 + l16;
        onesv[nt] = (n == T_) ? (short)0x3F80 : (short)0;
        int nr = n < T_ ? n : T_ - 1;
        tptr[nt] = tgt + ((size_t)b * T_ + nr) * HW_ + (size_t)seg * SEGP + quad * 8;
    }

    f32x4 accx[2][4], accs[2][4];
#pragma unroll
    for (int mt = 0; mt < 2; ++mt)
#pragma unroll
        for (int nt = 0; nt < 4; ++nt) {
            accx[mt][nt] = (f32x4)(0.f);
            accs[mt][nt] = (f32x4)(0.f);
        }
    float sneg[2] = {0.f, 0.f};

    float4 xrb[2][2][2];
    int4   trb[2][4][2];

    auto loadraw = [&](int ch, float4 xr[2][2], int4 tr[4][2]) {
        const int k = ch * 32;
#pragma unroll
        for (int mt = 0; mt < 2; ++mt) {
            xr[mt][0] = *(const float4*)(xptr[mt] + k);
            xr[mt][1] = *(const float4*)(xptr[mt] + k + 4);
        }
#pragma unroll
        for (int nt = 0; nt < 4; ++nt) {
            tr[nt][0] = *(const int4*)(tptr[nt] + k);
            tr[nt][1] = *(const int4*)(tptr[nt] + k + 4);
        }
    };

    auto compute = [&](float4 xr[2][2], int4 tr[4][2]) {
        bf16x8 tf[4];
#pragma unroll
        for (int nt = 0; nt < 4; ++nt)
#pragma unroll
            for (int h = 0; h < 2; ++h)
#pragma unroll
                for (int e = 0; e < 4; ++e) {
                    int v = (&tr[nt][h].x)[e];
                    tf[nt][h * 4 + e] = v ? (short)0x3F80 : onesv[nt];
                }
#pragma unroll
        for (int mt = 0; mt < 2; ++mt) {
            bf16x8 xf, sf;
            float sp = 0.f;
#pragma unroll
            for (int h = 0; h < 2; ++h)
#pragma unroll
                for (int e = 0; e < 4; ++e) {
                    float x = (&xr[mt][h].x)[e];
                    float ax = fabsf(x);
                    float ee = __expf(-ax);
                    float d = 1.f + ee;
                    float r1 = __builtin_amdgcn_rcpf(d);
                    float sg = (x >= 0.f) ? r1 : ee * r1;
                    sp += fmaxf(x, 0.f) + 0.69314718056f * __log2f(d);
                    xf[h * 4 + e] = aones[mt] ? (short)0x3F80 : (short)f2bf(x);
                    sf[h * 4 + e] = aones[mt] ? (short)0x3F80 : (short)f2bf(sg);
                }
            sneg[mt] += sp;
#pragma unroll
            for (int nt = 0; nt < 4; ++nt) {
                accx[mt][nt] = __builtin_amdgcn_mfma_f32_16x16x32_bf16(xf, tf[nt], accx[mt][nt], 0, 0, 0);
                accs[mt][nt] = __builtin_amdgcn_mfma_f32_16x16x32_bf16(sf, tf[nt], accs[mt][nt], 0, 0, 0);
            }
        }
    };

    loadraw(0, xrb[0], trb[0]);
#pragma unroll 2
    for (int ch = 0; ch < NK32P; ++ch) {
        const int cb = ch & 1;
        if (ch + 1 < NK32P) loadraw(ch + 1, xrb[cb ^ 1], trb[cb ^ 1]);
        compute(xrb[cb], trb[cb]);
    }

    float* d1 = ws + (size_t)(seg * B_ + b) * PTILE;
    float* d2 = d1 + D2OFF;

#pragma unroll
    for (int mt = 0; mt < 2; ++mt) {
        float v = sneg[mt];
        v += __shfl_xor(v, 16);
        v += __shfl_xor(v, 32);
        int m = (wave + mt * 4) * 16 + l16;
        if (quad == 0 && m < Q_) d1[(size_t)m * PCOLS + 51] = v;
    }
#pragma unroll
    for (int mt = 0; mt < 2; ++mt) {
        int mtile = (wave + mt * 4) * 16;
#pragma unroll
        for (int nt = 0; nt < 4; ++nt) {
            int n = nt * 16 + l16;
#pragma unroll
            for (int r = 0; r < 4; ++r) {
                int m = mtile + quad * 4 + r;
                if (m <= Q_ && n <= T_) {
                    size_t idx = (size_t)m * PCOLS + n;
                    d1[idx] = accx[mt][nt][r];
                    d2[idx] = accs[mt][nt][r];
                }
            }
        }
    }
}

// ======================= shared reduction (tiers A+B) =======================
// 4-way seg-split, float4 loads: grid (ceil(2*PBLK/4/256), 4); y sums 32 slabs
// into slab y*32. finalize_p2 combines the 4 surviving slabs.
__global__ void reduce_p4(float* __restrict__ ws) {
    int j = blockIdx.x * blockDim.x + threadIdx.x;
    const int Q4 = (int)(PBLK / 4);            // 10504
    if (j >= 2 * Q4) return;
    int y = blockIdx.y;
    size_t off = (j < Q4) ? ((size_t)j * 4) : (D2OFF + (size_t)(j - Q4) * 4);
    const float4* p = (const float4*)(ws + off);
    int s0 = y * (PSEG / 4);
    float a0 = 0.f, a1 = 0.f, a2 = 0.f, a3 = 0.f;
#pragma unroll 4
    for (int s = s0; s < s0 + PSEG / 4; ++s) {
        float4 v = p[(size_t)s * (PBLK / 4)];
        a0 += v.x; a1 += v.y; a2 += v.z; a3 += v.w;
    }
    float4 r; r.x = a0; r.y = a1; r.z = a2; r.w = a3;
    *(float4*)(ws + off + (size_t)s0 * PBLK) = r;
}

__global__ void finalize_p2(const float* __restrict__ ws, float* __restrict__ out) {
    int i = blockIdx.x * blockDim.x + threadIdx.x;
    if (i >= B_ * Q_ * T_) return;
    int b = i / (Q_ * T_);
    int r = i % (Q_ * T_);
    int q = r / T_;
    int t = r % T_;
    float dx = 0.f, ds = 0.f, ss = 0.f, sn = 0.f, stv = 0.f;
#pragma unroll
    for (int y = 0; y < 4; ++y) {
        const float* d1 = ws + (size_t)y * 32 * PBLK + (size_t)b * PTILE;
        const float* d2 = d1 + D2OFF;
        dx  += d1[(size_t)q * PCOLS + t];
        ds  += d2[(size_t)q * PCOLS + t];
        ss  += d2[(size_t)q * PCOLS + T_];
        sn  += d1[(size_t)q * PCOLS + 51];
        stv += d1[(size_t)Q_ * PCOLS + t];
    }
    float ce = (sn - dx) * (1.f / (float)HW_);
    float dice = 1.f - (2.f * ds + 1.f) / (ss + stv + 1.f);
    out[i] = ce + dice;
}

// ======================= legacy atomic fallback (verbatim) =======================
__global__ void zero_ws(float* ws) {
    int i = blockIdx.x * blockDim.x + threadIdx.x;
    if (i < WS_TOTAL) ws[i] = 0.f;
}

__global__ __launch_bounds__(256, 2) void gemm_fused(const float* __restrict__ pred,
                                                     const int* __restrict__ tgt,
                                                     float* __restrict__ ws) {
    const int seg = blockIdx.x;
    const int b   = blockIdx.y;
    const int tid = threadIdx.x;
    const int wave = tid >> 6;
    const int lane = tid & 63;
    const int quad = lane >> 4;
    const int l16  = lane & 15;

    const float* xptr[2];
#pragma unroll
    for (int mt = 0; mt < 2; ++mt) {
        int m = (wave + mt * 4) * 16 + l16;
        int mr = m < Q_ ? m : Q_ - 1;
        xptr[mt] = pred + ((size_t)b * Q_ + mr) * HW_ + (size_t)seg * SEG + quad * 8;
    }
    const int* tptr[4];
    int ones[4];
#pragma unroll
    for (int nt = 0; nt < 4; ++nt) {
        int n = nt * 16 + l16;
        ones[nt] = (n == T_);
        int nr = n < T_ ? n : T_ - 1;
        tptr[nt] = tgt + ((size_t)b * T_ + nr) * HW_ + (size_t)seg * SEG + quad * 8;
    }

    f32x4 accx[2][4], accs[2][4];
#pragma unroll
    for (int mt = 0; mt < 2; ++mt)
#pragma unroll
        for (int nt = 0; nt < 4; ++nt) {
            accx[mt][nt] = (f32x4)(0.f);
            accs[mt][nt] = (f32x4)(0.f);
        }
    float sneg[2] = {0.f, 0.f};
    float stq[4] = {0.f, 0.f, 0.f, 0.f};

    float4 xrb[2][2][2];
    int4   trb[2][4][2];

    auto loadraw = [&](int ch, float4 xr[2][2], int4 tr[4][2]) {
        const int k = ch * 32;
#pragma unroll
        for (int mt = 0; mt < 2; ++mt) {
            xr[mt][0] = *(const float4*)(xptr[mt] + k);
            xr[mt][1] = *(const float4*)(xptr[mt] + k + 4);
        }
#pragma unroll
        for (int nt = 0; nt < 4; ++nt) {
            tr[nt][0] = *(const int4*)(tptr[nt] + k);
            tr[nt][1] = *(const int4*)(tptr[nt] + k + 4);
        }
    };

    auto compute = [&](float4 xr[2][2], int4 tr[4][2]) {
        bf16x8 tf[4];
#pragma unroll
        for (int nt = 0; nt < 4; ++nt) {
            float cnt = 0.f;
#pragma unroll
            for (int h = 0; h < 2; ++h)
#pragma unroll
                for (int e = 0; e < 4; ++e) {
                    int v = (&tr[nt][h].x)[e];
                    tf[nt][h * 4 + e] = (v || ones[nt]) ? (short)0x3F80 : (short)0;
                    cnt += v ? 1.f : 0.f;
                }
            stq[nt] += cnt;
        }
#pragma unroll
        for (int mt = 0; mt < 2; ++mt) {
            bf16x8 xf, sf;
            float sp = 0.f;
#pragma unroll
            for (int h = 0; h < 2; ++h)
#pragma unroll
                for (int e = 0; e < 4; ++e) {
                    float x = (&xr[mt][h].x)[e];
                    float ax = fabsf(x);
                    float ee = __expf(-ax);
                    float d = 1.f + ee;
                    float r1 = __builtin_amdgcn_rcpf(d);
                    float sg = (x >= 0.f) ? r1 : ee * r1;
                    sp += fmaxf(x, 0.f) + 0.69314718056f * __log2f(d);
                    xf[h * 4 + e] = (short)f2bf(x);
                    sf[h * 4 + e] = (short)f2bf(sg);
                }
            sneg[mt] += sp;
#pragma unroll
            for (int nt = 0; nt < 4; ++nt) {
                accx[mt][nt] = __builtin_amdgcn_mfma_f32_16x16x32_bf16(xf, tf[nt], accx[mt][nt], 0, 0, 0);
                accs[mt][nt] = __builtin_amdgcn_mfma_f32_16x16x32_bf16(sf, tf[nt], accs[mt][nt], 0, 0, 0);
            }
        }
    };

    loadraw(0, xrb[0], trb[0]);
#pragma unroll 2
    for (int ch = 0; ch < NK32; ++ch) {
        const int cb = ch & 1;
        if (ch + 1 < NK32) loadraw(ch + 1, xrb[cb ^ 1], trb[cb ^ 1]);
        compute(xrb[cb], trb[cb]);
    }

#pragma unroll
    for (int mt = 0; mt < 2; ++mt) {
        float v = sneg[mt];
        v += __shfl_xor(v, 16);
        v += __shfl_xor(v, 32);
        int m = (wave + mt * 4) * 16 + l16;
        if (quad == 0 && m < Q_) atomicAdd(&ws[WS_SNEG + b * Q_ + m], v);
    }
    if (wave == 0) {
#pragma unroll
        for (int nt = 0; nt < 4; ++nt) {
            float v = stq[nt];
            v += __shfl_xor(v, 16);
            v += __shfl_xor(v, 32);
            int n = nt * 16 + l16;
            if (quad == 0 && n < T_) atomicAdd(&ws[WS_ST + b * T_ + n], v);
        }
    }
#pragma unroll
    for (int mt = 0; mt < 2; ++mt) {
        int mtile = (wave + mt * 4) * 16;
#pragma unroll
        for (int nt = 0; nt < 4; ++nt) {
            int n = nt * 16 + l16;
#pragma unroll
            for (int r = 0; r < 4; ++r) {
                int m = mtile + quad * 4 + r;
                if (m < Q_) {
                    size_t idx = ((size_t)b * Q_ + m) * NSTR + n;
                    if (n < T_) atomicAdd(&ws[WS_D1 + idx], accx[mt][nt][r]);
                    if (n <= T_) atomicAdd(&ws[WS_D2 + idx], accs[mt][nt][r]);
                }
            }
        }
    }
}

__global__ void finalize(const float* __restrict__ ws, float* __restrict__ out) {
    int i = blockIdx.x * blockDim.x + threadIdx.x;
    if (i >= B_ * Q_ * T_) return;
    int b = i / (Q_ * T_);
    int r = i % (Q_ * T_);
    int q = r / T_;
    int t = r % T_;
    float dx   = ws[WS_D1 + ((size_t)b * Q_ + q) * NSTR + t];
    float ds   = ws[WS_D2 + ((size_t)b * Q_ + q) * NSTR + t];
    float ssum = ws[WS_D2 + ((size_t)b * Q_ + q) * NSTR + T_];
    float st   = ws[WS_ST + b * T_ + t];
    float sneg = ws[WS_SNEG + b * Q_ + q];
    float ce = (sneg - dx) * (1.f / (float)HW_);
    float dice = 1.f - (2.f * ds + 1.f) / (ssum + st + 1.f);
    out[i] = ce + dice;
}

extern "C" void kernel_launch(void* const* d_in, const int* in_sizes, int n_in,
                              void* d_out, int out_size, void* d_ws, size_t ws_size,
                              hipStream_t stream) {
    const float* pred = (const float*)d_in[0];
    const int* tgt = (const int*)d_in[1];
    float* ws = (float*)d_ws;
    float* out = (float*)d_out;

    const int Q4 = (int)(PBLK / 4);
    dim3 rg((2 * Q4 + 255) / 256, 4, 1);

    if (ws_size >= WS2_NEEDED_BYTES) {
        // tier A: bitmask t + register-diet gemm (3 waves/SIMD)
        unsigned* bits = (unsigned*)(ws + BITS_FOFF);
        pack_t<<<2048, 256, 0, stream>>>(tgt, bits);
        dim3 g(PSEG, B_, 1);
        gemm_fused_p2<<<g, 256, 0, stream>>>(pred, bits, ws);
        reduce_p4<<<rg, 256, 0, stream>>>(ws);
        finalize_p2<<<(B_ * Q_ * T_ + 255) / 256, 256, 0, stream>>>(ws, out);
    } else if (ws_size >= WS_NEEDED_BYTES) {
        // tier B: round-3 proven path
        dim3 g(PSEG, B_, 1);
        gemm_fused_p<<<g, 256, 0, stream>>>(pred, tgt, ws);
        reduce_p4<<<rg, 256, 0, stream>>>(ws);
        finalize_p2<<<(B_ * Q_ * T_ + 255) / 256, 256, 0, stream>>>(ws, out);
    } else {
        // legacy atomic path
        zero_ws<<<(WS_TOTAL + 255) / 256, 256, 0, stream>>>(ws);
        dim3 g(NSEG, B_, 1);
        gemm_fused<<<g, 256, 0, stream>>>(pred, tgt, ws);
        finalize<<<(B_ * Q_ * T_ + 255) / 256, 256, 0, stream>>>(ws, out);
    }
}

// Round 5
// 393.523 us; speedup vs baseline: 1.0471x; 1.0471x over previous
//
#include <hip/hip_runtime.h>
#include <hip/hip_bf16.h>
#include <math.h>

#define B_ 8
#define Q_ 100
#define T_ 50
#define HW_ 65536

// ---------------- LDS-pipelined path (v5) ----------------
#define PSEG3 64
#define SEG3 (HW_ / PSEG3)         // 1024 K per block
#define NT3 (SEG3 / 32)            // 32 chunks of K=32
#define PF 2                       // LDS pipeline depth
#define PROWS 101                  // 100 q rows + ones-row (st)
#define PCOLS 52                   // 50 t + ssum col (50) + sneg col (51)
#define PTILE ((size_t)PROWS * PCOLS)          // 5252
#define PBLK ((size_t)B_ * PTILE)              // 42016 floats per seg per array
#define D2OFF3 ((size_t)PSEG3 * PBLK)
#define WS3_NEEDED_BYTES (2ull * D2OFF3 * 4ull)  // 21,512,192 B

// ---------------- legacy (atomic) fallback constants ----------------
#define NSEG 64
#define SEG (HW_ / NSEG)
#define NK32 (SEG / 32)
#define NSTR 52
#define DSZ (B_ * Q_ * NSTR)
#define WS_D1 0
#define WS_D2 DSZ
#define WS_SNEG (2 * DSZ)
#define WS_ST (2 * DSZ + B_ * Q_)
#define WS_TOTAL (2 * DSZ + B_ * Q_ + B_ * T_)

typedef __attribute__((ext_vector_type(8))) short bf16x8;
typedef __attribute__((ext_vector_type(4))) float f32x4;

__device__ __forceinline__ unsigned short f2bf(float f) {
    union { float f; unsigned u; } v; v.f = f;
    unsigned r = v.u + 0x7FFF + ((v.u >> 16) & 1);
    return (unsigned short)(r >> 16);
}

// packed pair bf16(a) | bf16(b)<<16 — lowers to v_cvt_pk_bf16_f32
__device__ __forceinline__ unsigned pkbf(float a, float b) {
    float2 f2; f2.x = a; f2.y = b;
    __hip_bfloat162 h2 = __float22bfloat162_rn(f2);
    unsigned u; __builtin_memcpy(&u, &h2, 4); return u;
}

// async global->LDS, 16 B per lane; LDS dest is wave-uniform base + lane*16
__device__ __forceinline__ void gld_lds16(const void* g, void* l) {
    __builtin_amdgcn_global_load_lds((const __attribute__((address_space(1))) void*)g,
                                     (__attribute__((address_space(3))) void*)l,
                                     16, 0, 0);
}

// ======================= v5 main kernel =======================
// Grid (PSEG3, B_) x 512 threads (8 waves). Each wave owns ONE 16-row m-tile
// (32 AGPR accumulators) so total regs stay <=128 -> 4 waves/SIMD (m69:
// occupancy bins at 64/128/256 total regs; rounds 2-4 sat in the 256 bin).
// x and t tiles are staged to LDS with global_load_lds (coalesced 8-rows-per-
// instruction: 4x fewer cache-line lookups than the MFMA-layout direct loads),
// 2-deep pipeline with counted vmcnt(3) + raw s_barrier. Chunk16 XOR-swizzle
// (write-side pre-swizzled global address, read-side XOR) keeps ds_read_b128
// at 2-way bank aliasing (free). Row m==100 => ones row (st); col n==50 =>
// ones column (ssum); sneg in col 51. Partials reduced by reduce_p3/finalize_p3.
__global__ __launch_bounds__(512, 4) void gemm_fused_p3(const float* __restrict__ pred,
                                                        const int* __restrict__ tgt,
                                                        float* __restrict__ ws) {
    const int seg = blockIdx.x;
    const int b   = blockIdx.y;
    const int tid = threadIdx.x;
    const int wave = tid >> 6;
    const int lane = tid & 63;
    const int quad = lane >> 4;
    const int l16  = lane & 15;

    __shared__ float xs[PF][128 * 32];   // 2 x 16 KB: 128 rows x 32 f32
    __shared__ int   tsh[PF][64 * 32];   // 2 x 8 KB:  64 rows x 32 i32

    // ---- staging source pointers (per-thread, pre-swizzled chunk) ----
    const int rA  = tid >> 3;                       // rows 0..63   (x issue 0, t issue)
    const int rB  = rA + 64;                        // rows 64..127 (x issue 1)
    const int cg  = (tid & 7) ^ (rA & 7);           // rB&7 == rA&7
    const int rBc = rB < Q_ ? rB : Q_ - 1;          // clamp garbage rows -> row 99 (finite)
    const int tnc = rA < T_ ? rA : T_ - 1;          // t rows >=50 clamped (masked later)
    const float* gx0 = pred + ((size_t)b * Q_ + rA)  * HW_ + (size_t)seg * SEG3 + cg * 4;
    const float* gx1 = pred + ((size_t)b * Q_ + rBc) * HW_ + (size_t)seg * SEG3 + cg * 4;
    const int*   gt  = tgt  + ((size_t)b * T_ + tnc) * HW_ + (size_t)seg * SEG3 + cg * 4;

    auto stage = [&](int ch, int slot) {
        const int ko = ch * 32;
        gld_lds16(gx0 + ko, &xs[slot][wave * 256]);          // rows  w*8..w*8+7
        gld_lds16(gx1 + ko, &xs[slot][2048 + wave * 256]);   // rows 64+w*8..
        gld_lds16(gt  + ko, &tsh[slot][wave * 256]);         // t rows w*8..
    };

    f32x4 accx[4], accs[4];
#pragma unroll
    for (int nt = 0; nt < 4; ++nt) { accx[nt] = (f32x4)(0.f); accs[nt] = (f32x4)(0.f); }
    float sneg = 0.f;

    const int aones = (wave * 16 + l16) == Q_;      // ones-row lane (wave 6, l16 4)
    const int srow  = l16 & 7;
    const int c0 = ((2 * quad)     ^ srow) * 4;     // swizzled 16B-chunk offsets (floats)
    const int c1 = ((2 * quad + 1) ^ srow) * 4;
    const int xrowoff = (wave * 16 + l16) * 32;

    stage(0, 0);
    stage(1, 1);

    int slot = 0;
    float4 xa, xb;
    int4 ta[4], tb[4];

    for (int ch = 0; ch < NT3; ++ch) {
        // wait for stage(ch) (own 3 loads), keep stage(ch+1) in flight
        if (ch + 1 < NT3) asm volatile("s_waitcnt vmcnt(3)" ::: "memory");
        else              asm volatile("s_waitcnt vmcnt(0)" ::: "memory");
        asm volatile("s_barrier" ::: "memory");      // everyone's stage(ch) done

        // ---- read phase: LDS -> regs ----
        {
            const float* xr = &xs[slot][xrowoff];
            xa = *(const float4*)(xr + c0);
            xb = *(const float4*)(xr + c1);
#pragma unroll
            for (int nt = 0; nt < 4; ++nt) {
                const int* tr = &tsh[slot][(nt * 16 + l16) * 32];
                ta[nt] = *(const int4*)(tr + c0);
                tb[nt] = *(const int4*)(tr + c1);
            }
        }
        asm volatile("s_waitcnt lgkmcnt(0)" ::: "memory");
        __builtin_amdgcn_sched_barrier(0);
        asm volatile("s_barrier" ::: "memory");      // all waves done reading slot

        if (ch + PF < NT3) stage(ch + PF, slot);     // overwrite slot; hides under math

        // ---- math phase ----
        bf16x8 tf[4];
#pragma unroll
        for (int nt = 0; nt < 4; ++nt) {
            short base = ((nt * 16 + l16) == T_) ? (short)0x3F80 : (short)0;
#pragma unroll
            for (int e = 0; e < 4; ++e) {
                tf[nt][e]     = (&ta[nt].x)[e] ? (short)0x3F80 : base;
                tf[nt][4 + e] = (&tb[nt].x)[e] ? (short)0x3F80 : base;
            }
        }
        float xe[8] = {xa.x, xa.y, xa.z, xa.w, xb.x, xb.y, xb.z, xb.w};
        float sg8[8];
        float sp = 0.f;
#pragma unroll
        for (int e = 0; e < 8; ++e) {
            float x = xe[e];
            float ax = fabsf(x);
            float ee = __expf(-ax);
            float d = 1.f + ee;
            float r1 = __builtin_amdgcn_rcpf(d);
            sg8[e] = (x >= 0.f) ? r1 : ee * r1;                // sigmoid
            sp += fmaxf(x, 0.f) + 0.69314718056f * __log2f(d); // softplus
        }
        sneg += sp;
        unsigned xu[4], su[4];
#pragma unroll
        for (int j = 0; j < 4; ++j) {
            xu[j] = aones ? 0x3F803F80u : pkbf(xe[2 * j], xe[2 * j + 1]);
            su[j] = aones ? 0x3F803F80u : pkbf(sg8[2 * j], sg8[2 * j + 1]);
        }
        bf16x8 xf, sf;
        __builtin_memcpy(&xf, xu, 16);
        __builtin_memcpy(&sf, su, 16);
#pragma unroll
        for (int nt = 0; nt < 4; ++nt) {
            accx[nt] = __builtin_amdgcn_mfma_f32_16x16x32_bf16(xf, tf[nt], accx[nt], 0, 0, 0);
            accs[nt] = __builtin_amdgcn_mfma_f32_16x16x32_bf16(sf, tf[nt], accs[nt], 0, 0, 0);
        }
        slot ^= 1;
    }

    // ---- epilogue: coalesced partial stores, zero atomics ----
    float* d1 = ws + (size_t)(seg * B_ + b) * PTILE;
    float* d2 = d1 + D2OFF3;

    {
        float v = sneg;
        v += __shfl_xor(v, 16);
        v += __shfl_xor(v, 32);
        int m = wave * 16 + l16;
        if (quad == 0 && m < Q_) d1[(size_t)m * PCOLS + 51] = v;
    }
    const int mtile = wave * 16;
#pragma unroll
    for (int nt = 0; nt < 4; ++nt) {
        int n = nt * 16 + l16;
#pragma unroll
        for (int r = 0; r < 4; ++r) {
            int m = mtile + quad * 4 + r;
            if (m <= Q_ && n <= T_) {   // includes ones-row (st) and ssum col
                size_t idx = (size_t)m * PCOLS + n;
                d1[idx] = accx[nt][r];
                d2[idx] = accs[nt][r];
            }
        }
    }
}

// 4-way seg-split reduction, float4 loads: y sums 16 slabs into slab y*16.
__global__ void reduce_p3(float* __restrict__ ws) {
    int j = blockIdx.x * blockDim.x + threadIdx.x;
    const int Q4 = (int)(PBLK / 4);            // 10504
    if (j >= 2 * Q4) return;
    int y = blockIdx.y;
    size_t off = (j < Q4) ? ((size_t)j * 4) : (D2OFF3 + (size_t)(j - Q4) * 4);
    const float4* p = (const float4*)(ws + off);
    int s0 = y * (PSEG3 / 4);
    float a0 = 0.f, a1 = 0.f, a2 = 0.f, a3 = 0.f;
#pragma unroll 4
    for (int s = s0; s < s0 + PSEG3 / 4; ++s) {
        float4 v = p[(size_t)s * (PBLK / 4)];
        a0 += v.x; a1 += v.y; a2 += v.z; a3 += v.w;
    }
    float4 r; r.x = a0; r.y = a1; r.z = a2; r.w = a3;
    *(float4*)(ws + off + (size_t)s0 * PBLK) = r;
}

__global__ void finalize_p3(const float* __restrict__ ws, float* __restrict__ out) {
    int i = blockIdx.x * blockDim.x + threadIdx.x;
    if (i >= B_ * Q_ * T_) return;
    int b = i / (Q_ * T_);
    int r = i % (Q_ * T_);
    int q = r / T_;
    int t = r % T_;
    float dx = 0.f, ds = 0.f, ss = 0.f, sn = 0.f, stv = 0.f;
#pragma unroll
    for (int y = 0; y < 4; ++y) {
        const float* d1 = ws + (size_t)y * (PSEG3 / 4) * PBLK + (size_t)b * PTILE;
        const float* d2 = d1 + D2OFF3;
        dx  += d1[(size_t)q * PCOLS + t];
        ds  += d2[(size_t)q * PCOLS + t];
        ss  += d2[(size_t)q * PCOLS + T_];
        sn  += d1[(size_t)q * PCOLS + 51];
        stv += d1[(size_t)Q_ * PCOLS + t];
    }
    float ce = (sn - dx) * (1.f / (float)HW_);
    float dice = 1.f - (2.f * ds + 1.f) / (ss + stv + 1.f);
    out[i] = ce + dice;
}

// ======================= legacy atomic fallback (verbatim round-0) =======================
__global__ void zero_ws(float* ws) {
    int i = blockIdx.x * blockDim.x + threadIdx.x;
    if (i < WS_TOTAL) ws[i] = 0.f;
}

__global__ __launch_bounds__(256, 2) void gemm_fused(const float* __restrict__ pred,
                                                     const int* __restrict__ tgt,
                                                     float* __restrict__ ws) {
    const int seg = blockIdx.x;
    const int b   = blockIdx.y;
    const int tid = threadIdx.x;
    const int wave = tid >> 6;
    const int lane = tid & 63;
    const int quad = lane >> 4;
    const int l16  = lane & 15;

    const float* xptr[2];
#pragma unroll
    for (int mt = 0; mt < 2; ++mt) {
        int m = (wave + mt * 4) * 16 + l16;
        int mr = m < Q_ ? m : Q_ - 1;
        xptr[mt] = pred + ((size_t)b * Q_ + mr) * HW_ + (size_t)seg * SEG + quad * 8;
    }
    const int* tptr[4];
    int ones[4];
#pragma unroll
    for (int nt = 0; nt < 4; ++nt) {
        int n = nt * 16 + l16;
        ones[nt] = (n == T_);
        int nr = n < T_ ? n : T_ - 1;
        tptr[nt] = tgt + ((size_t)b * T_ + nr) * HW_ + (size_t)seg * SEG + quad * 8;
    }

    f32x4 accx[2][4], accs[2][4];
#pragma unroll
    for (int mt = 0; mt < 2; ++mt)
#pragma unroll
        for (int nt = 0; nt < 4; ++nt) {
            accx[mt][nt] = (f32x4)(0.f);
            accs[mt][nt] = (f32x4)(0.f);
        }
    float sneg[2] = {0.f, 0.f};
    float stq[4] = {0.f, 0.f, 0.f, 0.f};

    float4 xrb[2][2][2];
    int4   trb[2][4][2];

    auto loadraw = [&](int ch, float4 xr[2][2], int4 tr[4][2]) {
        const int k = ch * 32;
#pragma unroll
        for (int mt = 0; mt < 2; ++mt) {
            xr[mt][0] = *(const float4*)(xptr[mt] + k);
            xr[mt][1] = *(const float4*)(xptr[mt] + k + 4);
        }
#pragma unroll
        for (int nt = 0; nt < 4; ++nt) {
            tr[nt][0] = *(const int4*)(tptr[nt] + k);
            tr[nt][1] = *(const int4*)(tptr[nt] + k + 4);
        }
    };

    auto compute = [&](float4 xr[2][2], int4 tr[4][2]) {
        bf16x8 tf[4];
#pragma unroll
        for (int nt = 0; nt < 4; ++nt) {
            float cnt = 0.f;
#pragma unroll
            for (int h = 0; h < 2; ++h)
#pragma unroll
                for (int e = 0; e < 4; ++e) {
                    int v = (&tr[nt][h].x)[e];
                    tf[nt][h * 4 + e] = (v || ones[nt]) ? (short)0x3F80 : (short)0;
                    cnt += v ? 1.f : 0.f;
                }
            stq[nt] += cnt;
        }
#pragma unroll
        for (int mt = 0; mt < 2; ++mt) {
            bf16x8 xf, sf;
            float sp = 0.f;
#pragma unroll
            for (int h = 0; h < 2; ++h)
#pragma unroll
                for (int e = 0; e < 4; ++e) {
                    float x = (&xr[mt][h].x)[e];
                    float ax = fabsf(x);
                    float ee = __expf(-ax);
                    float d = 1.f + ee;
                    float r1 = __builtin_amdgcn_rcpf(d);
                    float sg = (x >= 0.f) ? r1 : ee * r1;
                    sp += fmaxf(x, 0.f) + 0.69314718056f * __log2f(d);
                    xf[h * 4 + e] = (short)f2bf(x);
                    sf[h * 4 + e] = (short)f2bf(sg);
                }
            sneg[mt] += sp;
#pragma unroll
            for (int nt = 0; nt < 4; ++nt) {
                accx[mt][nt] = __builtin_amdgcn_mfma_f32_16x16x32_bf16(xf, tf[nt], accx[mt][nt], 0, 0, 0);
                accs[mt][nt] = __builtin_amdgcn_mfma_f32_16x16x32_bf16(sf, tf[nt], accs[mt][nt], 0, 0, 0);
            }
        }
    };

    loadraw(0, xrb[0], trb[0]);
#pragma unroll 2
    for (int ch = 0; ch < NK32; ++ch) {
        const int cb = ch & 1;
        if (ch + 1 < NK32) loadraw(ch + 1, xrb[cb ^ 1], trb[cb ^ 1]);
        compute(xrb[cb], trb[cb]);
    }

#pragma unroll
    for (int mt = 0; mt < 2; ++mt) {
        float v = sneg[mt];
        v += __shfl_xor(v, 16);
        v += __shfl_xor(v, 32);
        int m = (wave + mt * 4) * 16 + l16;
        if (quad == 0 && m < Q_) atomicAdd(&ws[WS_SNEG + b * Q_ + m], v);
    }
    if (wave == 0) {
#pragma unroll
        for (int nt = 0; nt < 4; ++nt) {
            float v = stq[nt];
            v += __shfl_xor(v, 16);
            v += __shfl_xor(v, 32);
            int n = nt * 16 + l16;
            if (quad == 0 && n < T_) atomicAdd(&ws[WS_ST + b * T_ + n], v);
        }
    }
#pragma unroll
    for (int mt = 0; mt < 2; ++mt) {
        int mtile = (wave + mt * 4) * 16;
#pragma unroll
        for (int nt = 0; nt < 4; ++nt) {
            int n = nt * 16 + l16;
#pragma unroll
            for (int r = 0; r < 4; ++r) {
                int m = mtile + quad * 4 + r;
                if (m < Q_) {
                    size_t idx = ((size_t)b * Q_ + m) * NSTR + n;
                    if (n < T_) atomicAdd(&ws[WS_D1 + idx], accx[mt][nt][r]);
                    if (n <= T_) atomicAdd(&ws[WS_D2 + idx], accs[mt][nt][r]);
                }
            }
        }
    }
}

__global__ void finalize(const float* __restrict__ ws, float* __restrict__ out) {
    int i = blockIdx.x * blockDim.x + threadIdx.x;
    if (i >= B_ * Q_ * T_) return;
    int b = i / (Q_ * T_);
    int r = i % (Q_ * T_);
    int q = r / T_;
    int t = r % T_;
    float dx   = ws[WS_D1 + ((size_t)b * Q_ + q) * NSTR + t];
    float ds   = ws[WS_D2 + ((size_t)b * Q_ + q) * NSTR + t];
    float ssum = ws[WS_D2 + ((size_t)b * Q_ + q) * NSTR + T_];
    float st   = ws[WS_ST + b * T_ + t];
    float sneg = ws[WS_SNEG + b * Q_ + q];
    float ce = (sneg - dx) * (1.f / (float)HW_);
    float dice = 1.f - (2.f * ds + 1.f) / (ssum + st + 1.f);
    out[i] = ce + dice;
}

extern "C" void kernel_launch(void* const* d_in, const int* in_sizes, int n_in,
                              void* d_out, int out_size, void* d_ws, size_t ws_size,
                              hipStream_t stream) {
    const float* pred = (const float*)d_in[0];
    const int* tgt = (const int*)d_in[1];
    float* ws = (float*)d_ws;
    float* out = (float*)d_out;

    if (ws_size >= WS3_NEEDED_BYTES) {
        // v5: LDS-pipelined, atomic-free, 21.5 MB ws
        dim3 g(PSEG3, B_, 1);
        gemm_fused_p3<<<g, 512, 0, stream>>>(pred, tgt, ws);
        const int Q4 = (int)(PBLK / 4);
        dim3 rg((2 * Q4 + 255) / 256, 4, 1);
        reduce_p3<<<rg, 256, 0, stream>>>(ws);
        finalize_p3<<<(B_ * Q_ * T_ + 255) / 256, 256, 0, stream>>>(ws, out);
    } else {
        // legacy atomic path (tiny ws)
        zero_ws<<<(WS_TOTAL + 255) / 256, 256, 0, stream>>>(ws);
        dim3 g(NSEG, B_, 1);
        gemm_fused<<<g, 256, 0, stream>>>(pred, tgt, ws);
        finalize<<<(B_ * Q_ * T_ + 255) / 256, 256, 0, stream>>>(ws, out);
    }
}